// Round 15
// baseline (807.852 us; speedup 1.0000x reference)
//
#include <hip/hip_runtime.h>

// ---------------------------------------------------------------------------
// Round 15: edge-balanced layer kernels. One block per 128-node range; the
// range's contiguous CSR edge list is split into equal per-thread chunks
// (degree imbalance absorbed inside the block). Threads accumulate O[16][u]
// in registers per node-segment, flush via LDS atomicAdd (ds_add_f32) into a
// per-node Oacc (stride 68 = bank-spread), then thread t contracts node t's
// Oacc with LDS-staged W2/G. edata now stores the packed {src<<8|ln} so the
// layer can recover the local node id without touching offs2 per edge.
// CSR build (k_bin/k_build/k_emb) unchanged except k_emb stores pkd.
// ---------------------------------------------------------------------------

#define BCAP 4608      // bucket capacity: mean 4096 + 8 sigma
#define NBMAX 400
#define OSTR 68        // Oacc per-node stride (floats): 16B-aligned, bank-spread

__device__ __forceinline__ float sus_f(float x) {
    return x > 0.0f ? __expf(-1.0f / x) : 0.0f;
}

__device__ __forceinline__ float uload(const float* p) {
    return __uint_as_float(__builtin_amdgcn_readfirstlane(__float_as_uint(*p)));
}

// --- pass 1: coarse binning, 4 B packed {src<<8 | dst&255}; block 0 also
// computes G[k][u][c] = sum_w fc3_w2[k][u*16+w] * conv_w[c][w] ---------------
__global__ __launch_bounds__(256) void k_bin(
    const int* __restrict__ src, const int* __restrict__ dst,
    int* __restrict__ gcur, int* __restrict__ ptmp,
    const float* __restrict__ fc3w2, const float* __restrict__ cw,
    float* __restrict__ gbuf,
    int nedges, int nb)
{
    __shared__ int cnt[NBMAX];
    __shared__ int gb[NBMAX];
    for (int b = threadIdx.x; b < nb; b += 256) cnt[b] = 0;
    __syncthreads();

    int base = blockIdx.x * 2048 + threadIdx.x * 8;
    int pk[8]; int bk[8]; short r[8];
    int ss[8], dd[8];
    if (base + 7 < nedges) {
        int4 s0 = *(const int4*)&src[base];
        int4 s1 = *(const int4*)&src[base + 4];
        int4 d0 = *(const int4*)&dst[base];
        int4 d1 = *(const int4*)&dst[base + 4];
        ss[0]=s0.x; ss[1]=s0.y; ss[2]=s0.z; ss[3]=s0.w;
        ss[4]=s1.x; ss[5]=s1.y; ss[6]=s1.z; ss[7]=s1.w;
        dd[0]=d0.x; dd[1]=d0.y; dd[2]=d0.z; dd[3]=d0.w;
        dd[4]=d1.x; dd[5]=d1.y; dd[6]=d1.z; dd[7]=d1.w;
        #pragma unroll
        for (int i = 0; i < 8; ++i) {
            int b = dd[i] >> 8;
            bk[i] = b;
            pk[i] = (ss[i] << 8) | (dd[i] & 255);
            r[i] = (short)atomicAdd(&cnt[b], 1);
        }
    } else {
        #pragma unroll
        for (int i = 0; i < 8; ++i) {
            int e = base + i;
            if (e < nedges) {
                int s = src[e], t = dst[e];
                int b = t >> 8;
                bk[i] = b;
                pk[i] = (s << 8) | (t & 255);
                r[i] = (short)atomicAdd(&cnt[b], 1);
            } else bk[i] = -1;
        }
    }
    __syncthreads();
    for (int b = threadIdx.x; b < nb; b += 256) {
        int c = cnt[b];
        gb[b] = c > 0 ? atomicAdd(&gcur[b], c) : 0;
    }
    __syncthreads();
    #pragma unroll
    for (int i = 0; i < 8; ++i) {
        if (bk[i] >= 0) {
            int p = gb[bk[i]] + (int)r[i];
            if (p < BCAP)   // statistically impossible overflow guard
                ptmp[bk[i] * BCAP + p] = pk[i];
        }
    }

    if (blockIdx.x == 0 && threadIdx.x < 128) {
        int idx = threadIdx.x;          // k*8 + u*2 + c
        int k = idx >> 3, u = (idx >> 1) & 3, c = idx & 1;
        float s = 0.0f;
        #pragma unroll
        for (int w = 0; w < 16; ++w)
            s = fmaf(fc3w2[k * 64 + u * 16 + w], cw[c * 16 + w], s);
        gbuf[idx] = s;
    }
}

// --- pass 2: per-bucket histogram/scan/permute (all in LDS, coalesced out) ---
__global__ __launch_bounds__(256) void k_build(
    const int* __restrict__ gcur, const int* __restrict__ ptmp,
    int* __restrict__ pidx, int2* __restrict__ offs2,
    int n, int nb)
{
    int b = blockIdx.x;
    int cnt = gcur[b]; if (cnt > BCAP) cnt = BCAP;

    __shared__ int stage[BCAP];
    __shared__ int perm[BCAP];
    __shared__ int deg[256];
    __shared__ int loffs[256];
    __shared__ int cur[256];

    const int* tin = ptmp + b * BCAP;
    for (int j = threadIdx.x; j < cnt; j += 256) stage[j] = tin[j];
    deg[threadIdx.x] = 0;
    __syncthreads();

    for (int j = threadIdx.x; j < cnt; j += 256)
        atomicAdd(&deg[stage[j] & 255], 1);
    __syncthreads();

    {
        int t = threadIdx.x;
        int v = deg[t];
        loffs[t] = v; __syncthreads();
        for (int off = 1; off < 256; off <<= 1) {
            int val = (t >= off) ? loffs[t - off] : 0;
            __syncthreads();
            loffs[t] += val;
            __syncthreads();
        }
        int incl = loffs[t];
        __syncthreads();
        loffs[t] = incl - v;
        cur[t] = incl - v;
        __syncthreads();
    }

    {
        int nid0 = b << 8;
        int nn = n - nid0; if (nn > 256) nn = 256;
        int t = threadIdx.x;
        if (t < nn) {
            int st = b * BCAP + loffs[t];
            offs2[nid0 + t] = make_int2(st, st + deg[t]);
        }
    }

    for (int j = threadIdx.x; j < cnt; j += 256) {
        int pkd = stage[j];
        perm[atomicAdd(&cur[pkd & 255], 1)] = pkd;
    }
    __syncthreads();

    int* tout = pidx + b * BCAP;
    for (int j = threadIdx.x; j < cnt; j += 256) tout[j] = perm[j];
}

// --- pass 3: edge-parallel emb; record = {pkd, e0, e1, e2} -------------------
__global__ __launch_bounds__(256) void k_emb(
    const float* __restrict__ pos, const int* __restrict__ gcur,
    const int* __restrict__ pidx, float4* __restrict__ ebuf)
{
    int b = blockIdx.y;
    int j = blockIdx.x * 256 + threadIdx.x;
    if (j >= gcur[b]) return;
    int pkd = pidx[b * BCAP + j];
    int s = pkd >> 8;
    int t = (b << 8) | (pkd & 255);
    float dx = pos[3 * t + 0] - pos[3 * s + 0];
    float dy = pos[3 * t + 1] - pos[3 * s + 1];
    float dz = pos[3 * t + 2] - pos[3 * s + 2];
    float d = sqrtf(dx * dx + dy * dy + dz * dz);
    const float C = 1.14136f * 7.3890560989306495f; // 1.14136 * e^2
    float e0, e1, e2;
    { float f = (d - 0.75f) * (1.0f / 0.75f);
      e0 = C * sus_f(f + 1.0f) * sus_f(1.0f - f); }
    { float f = (d - 1.50f) * (1.0f / 0.75f);
      e1 = C * sus_f(f + 1.0f) * sus_f(1.0f - f); }
    { float f = (d - 2.25f) * (1.0f / 0.75f);
      e2 = C * sus_f(f + 1.0f) * sus_f(1.0f - f); }
    ebuf[(size_t)b * BCAP + j] = make_float4(__int_as_float(pkd), e0, e1, e2);
}

// --- layers: edge-balanced blocks, LDS segmented reduction -------------------
// Block handles nodes [128*bid, 128*bid+nn). Edge list for the range is
// contiguous (bucket-padded CSR); threads take equal contiguous chunks.

// Layer 1: x = feat[3] (u<4 slot unused).
__global__ __launch_bounds__(256) void k_layer_l1(
    const float* __restrict__ feat, const float4* __restrict__ edata,
    const int2* __restrict__ offs2,
    const float* __restrict__ w1, const float* __restrict__ w2,
    float* __restrict__ xout, int n)
{
    __shared__ float Oacc[128 * OSTR];
    __shared__ float lw[16 * 20];
    if (threadIdx.x < 192) {
        int k = threadIdx.x / 12, r = threadIdx.x % 12;
        lw[k * 20 + r] = w2[k * 12 + r];
    }
    for (int i = threadIdx.x; i < 128 * OSTR; i += 256) Oacc[i] = 0.0f;
    __syncthreads();

    int base = blockIdx.x * 128;
    int nn = n - base; if (nn > 128) nn = 128;
    int e0 = offs2[base].x;
    int e1 = offs2[base + nn - 1].y;
    int cnt = e1 - e0;
    int chunk = (cnt + 255) >> 8;
    int js = e0 + threadIdx.x * chunk;
    int je = js + chunk; if (je > e1) je = e1;
    int lnbase = base & 255;

    float w1r[3][16];
    #pragma unroll
    for (int j = 0; j < 3; ++j)
        #pragma unroll
        for (int k = 0; k < 16; ++k) w1r[j][k] = uload(&w1[j * 16 + k]);

    float O[16][3];
    int cur = -1;
    for (int j = js; j < je; ++j) {
        float4 ed = edata[j];
        int pkd = __float_as_int(ed.x);
        int ln = (pkd & 255) - lnbase;
        int s = pkd >> 8;
        if (ln != cur) {
            if (cur >= 0) {
                #pragma unroll
                for (int k = 0; k < 16; ++k) {
                    atomicAdd(&Oacc[cur * OSTR + k * 4 + 0], O[k][0]);
                    atomicAdd(&Oacc[cur * OSTR + k * 4 + 1], O[k][1]);
                    atomicAdd(&Oacc[cur * OSTR + k * 4 + 2], O[k][2]);
                }
            }
            cur = ln;
            #pragma unroll
            for (int k = 0; k < 16; ++k) { O[k][0] = 0.f; O[k][1] = 0.f; O[k][2] = 0.f; }
        }
        float f0 = feat[3 * s + 0], f1 = feat[3 * s + 1], f2 = feat[3 * s + 2];
        #pragma unroll
        for (int k = 0; k < 16; ++k) {
            float a = fmaf(ed.y, w1r[0][k], fmaf(ed.z, w1r[1][k], ed.w * w1r[2][k]));
            float h = a > 0.0f ? a : 0.0f;
            O[k][0] = fmaf(h, f0, O[k][0]);
            O[k][1] = fmaf(h, f1, O[k][1]);
            O[k][2] = fmaf(h, f2, O[k][2]);
        }
    }
    if (cur >= 0) {
        #pragma unroll
        for (int k = 0; k < 16; ++k) {
            atomicAdd(&Oacc[cur * OSTR + k * 4 + 0], O[k][0]);
            atomicAdd(&Oacc[cur * OSTR + k * 4 + 1], O[k][1]);
            atomicAdd(&Oacc[cur * OSTR + k * 4 + 2], O[k][2]);
        }
    }
    __syncthreads();

    int t = threadIdx.x;
    if (t < nn) {
        float p0 = 0.f, p1 = 0.f, p2 = 0.f, p3 = 0.f;
        #pragma unroll
        for (int k = 0; k < 16; ++k) {
            float4 o = *(const float4*)&Oacc[t * OSTR + k * 4];
            const float4 q0 = *(const float4*)&lw[k * 20 + 0];
            const float4 q1 = *(const float4*)&lw[k * 20 + 4];
            const float4 q2 = *(const float4*)&lw[k * 20 + 8];
            p0 = fmaf(o.x, q0.x, fmaf(o.y, q1.x, fmaf(o.z, q2.x, p0)));
            p1 = fmaf(o.x, q0.y, fmaf(o.y, q1.y, fmaf(o.z, q2.y, p1)));
            p2 = fmaf(o.x, q0.z, fmaf(o.y, q1.z, fmaf(o.z, q2.z, p2)));
            p3 = fmaf(o.x, q0.w, fmaf(o.y, q1.w, fmaf(o.z, q2.w, p3)));
        }
        const float S = 0.051031036307982884f; // sqrt2/sqrt3/16
        float4 o; o.x = p0 * S; o.y = p1 * S; o.z = p2 * S; o.w = p3 * S;
        ((float4*)xout)[base + t] = o;
    }
}

// Core layers: x float4.
__global__ __launch_bounds__(256) void k_layer_core(
    const float4* __restrict__ xin, const float4* __restrict__ edata,
    const int2* __restrict__ offs2,
    const float* __restrict__ w1, const float* __restrict__ w2,
    float* __restrict__ xout, int n)
{
    __shared__ float Oacc[128 * OSTR];
    __shared__ float lw[16 * 20];
    {
        int k = threadIdx.x >> 4, r = threadIdx.x & 15;
        lw[k * 20 + r] = w2[k * 48 + r];
    }
    for (int i = threadIdx.x; i < 128 * OSTR; i += 256) Oacc[i] = 0.0f;
    __syncthreads();

    int base = blockIdx.x * 128;
    int nn = n - base; if (nn > 128) nn = 128;
    int e0 = offs2[base].x;
    int e1 = offs2[base + nn - 1].y;
    int cnt = e1 - e0;
    int chunk = (cnt + 255) >> 8;
    int js = e0 + threadIdx.x * chunk;
    int je = js + chunk; if (je > e1) je = e1;
    int lnbase = base & 255;

    float w1r[3][16];
    #pragma unroll
    for (int j = 0; j < 3; ++j)
        #pragma unroll
        for (int k = 0; k < 16; ++k) w1r[j][k] = uload(&w1[j * 16 + k]);

    float O[16][4];
    int cur = -1;
    for (int j = js; j < je; ++j) {
        float4 ed = edata[j];
        int pkd = __float_as_int(ed.x);
        int ln = (pkd & 255) - lnbase;
        int s = pkd >> 8;
        if (ln != cur) {
            if (cur >= 0) {
                #pragma unroll
                for (int k = 0; k < 16; ++k) {
                    atomicAdd(&Oacc[cur * OSTR + k * 4 + 0], O[k][0]);
                    atomicAdd(&Oacc[cur * OSTR + k * 4 + 1], O[k][1]);
                    atomicAdd(&Oacc[cur * OSTR + k * 4 + 2], O[k][2]);
                    atomicAdd(&Oacc[cur * OSTR + k * 4 + 3], O[k][3]);
                }
            }
            cur = ln;
            #pragma unroll
            for (int k = 0; k < 16; ++k) {
                O[k][0] = 0.f; O[k][1] = 0.f; O[k][2] = 0.f; O[k][3] = 0.f;
            }
        }
        float4 x = xin[s];
        #pragma unroll
        for (int k = 0; k < 16; ++k) {
            float a = fmaf(ed.y, w1r[0][k], fmaf(ed.z, w1r[1][k], ed.w * w1r[2][k]));
            float h = a > 0.0f ? a : 0.0f;
            O[k][0] = fmaf(h, x.x, O[k][0]);
            O[k][1] = fmaf(h, x.y, O[k][1]);
            O[k][2] = fmaf(h, x.z, O[k][2]);
            O[k][3] = fmaf(h, x.w, O[k][3]);
        }
    }
    if (cur >= 0) {
        #pragma unroll
        for (int k = 0; k < 16; ++k) {
            atomicAdd(&Oacc[cur * OSTR + k * 4 + 0], O[k][0]);
            atomicAdd(&Oacc[cur * OSTR + k * 4 + 1], O[k][1]);
            atomicAdd(&Oacc[cur * OSTR + k * 4 + 2], O[k][2]);
            atomicAdd(&Oacc[cur * OSTR + k * 4 + 3], O[k][3]);
        }
    }
    __syncthreads();

    int t = threadIdx.x;
    if (t < nn) {
        float p0 = 0.f, p1 = 0.f, p2 = 0.f, p3 = 0.f;
        #pragma unroll
        for (int k = 0; k < 16; ++k) {
            float4 o = *(const float4*)&Oacc[t * OSTR + k * 4];
            const float4 q0 = *(const float4*)&lw[k * 20 + 0];
            const float4 q1 = *(const float4*)&lw[k * 20 + 4];
            const float4 q2 = *(const float4*)&lw[k * 20 + 8];
            const float4 q3 = *(const float4*)&lw[k * 20 + 12];
            p0 = fmaf(o.x, q0.x, fmaf(o.y, q1.x, fmaf(o.z, q2.x, fmaf(o.w, q3.x, p0))));
            p1 = fmaf(o.x, q0.y, fmaf(o.y, q1.y, fmaf(o.z, q2.y, fmaf(o.w, q3.y, p1))));
            p2 = fmaf(o.x, q0.z, fmaf(o.y, q1.z, fmaf(o.z, q2.z, fmaf(o.w, q3.z, p2))));
            p3 = fmaf(o.x, q0.w, fmaf(o.y, q1.w, fmaf(o.z, q2.w, fmaf(o.w, q3.w, p3))));
        }
        const float S = 0.04419417382415922f; // sqrt2*0.5/16
        float4 o; o.x = p0 * S; o.y = p1 * S; o.z = p2 * S; o.w = p3 * S;
        ((float4*)xout)[base + t] = o;
    }
}

// fc3 + folded 1x1 conv via G[16][4][2].
__global__ __launch_bounds__(256) void k_layer_fc3(
    const float4* __restrict__ xin, const float4* __restrict__ edata,
    const int2* __restrict__ offs2,
    const float* __restrict__ w1, const float* __restrict__ gbuf,
    const float* __restrict__ cb,
    float* __restrict__ out, int n)
{
    __shared__ float Oacc[128 * OSTR];
    __shared__ float lg[128];
    if (threadIdx.x < 128) lg[threadIdx.x] = gbuf[threadIdx.x];
    for (int i = threadIdx.x; i < 128 * OSTR; i += 256) Oacc[i] = 0.0f;
    __syncthreads();

    int base = blockIdx.x * 128;
    int nn = n - base; if (nn > 128) nn = 128;
    int e0 = offs2[base].x;
    int e1 = offs2[base + nn - 1].y;
    int cnt = e1 - e0;
    int chunk = (cnt + 255) >> 8;
    int js = e0 + threadIdx.x * chunk;
    int je = js + chunk; if (je > e1) je = e1;
    int lnbase = base & 255;

    float w1r[3][16];
    #pragma unroll
    for (int j = 0; j < 3; ++j)
        #pragma unroll
        for (int k = 0; k < 16; ++k) w1r[j][k] = uload(&w1[j * 16 + k]);

    float O[16][4];
    int cur = -1;
    for (int j = js; j < je; ++j) {
        float4 ed = edata[j];
        int pkd = __float_as_int(ed.x);
        int ln = (pkd & 255) - lnbase;
        int s = pkd >> 8;
        if (ln != cur) {
            if (cur >= 0) {
                #pragma unroll
                for (int k = 0; k < 16; ++k) {
                    atomicAdd(&Oacc[cur * OSTR + k * 4 + 0], O[k][0]);
                    atomicAdd(&Oacc[cur * OSTR + k * 4 + 1], O[k][1]);
                    atomicAdd(&Oacc[cur * OSTR + k * 4 + 2], O[k][2]);
                    atomicAdd(&Oacc[cur * OSTR + k * 4 + 3], O[k][3]);
                }
            }
            cur = ln;
            #pragma unroll
            for (int k = 0; k < 16; ++k) {
                O[k][0] = 0.f; O[k][1] = 0.f; O[k][2] = 0.f; O[k][3] = 0.f;
            }
        }
        float4 x = xin[s];
        #pragma unroll
        for (int k = 0; k < 16; ++k) {
            float a = fmaf(ed.y, w1r[0][k], fmaf(ed.z, w1r[1][k], ed.w * w1r[2][k]));
            float h = a > 0.0f ? a : 0.0f;
            O[k][0] = fmaf(h, x.x, O[k][0]);
            O[k][1] = fmaf(h, x.y, O[k][1]);
            O[k][2] = fmaf(h, x.z, O[k][2]);
            O[k][3] = fmaf(h, x.w, O[k][3]);
        }
    }
    if (cur >= 0) {
        #pragma unroll
        for (int k = 0; k < 16; ++k) {
            atomicAdd(&Oacc[cur * OSTR + k * 4 + 0], O[k][0]);
            atomicAdd(&Oacc[cur * OSTR + k * 4 + 1], O[k][1]);
            atomicAdd(&Oacc[cur * OSTR + k * 4 + 2], O[k][2]);
            atomicAdd(&Oacc[cur * OSTR + k * 4 + 3], O[k][3]);
        }
    }
    __syncthreads();

    int t = threadIdx.x;
    if (t < nn) {
        float a0 = 0.f, a1 = 0.f;
        #pragma unroll
        for (int k = 0; k < 16; ++k) {
            float4 o = *(const float4*)&Oacc[t * OSTR + k * 4];
            const float4 g0 = *(const float4*)&lg[k * 8 + 0]; // (u0c0,u0c1,u1c0,u1c1)
            const float4 g1 = *(const float4*)&lg[k * 8 + 4]; // (u2c0,u2c1,u3c0,u3c1)
            a0 = fmaf(o.x, g0.x, fmaf(o.y, g0.z, fmaf(o.z, g1.x, fmaf(o.w, g1.z, a0))));
            a1 = fmaf(o.x, g0.y, fmaf(o.y, g0.w, fmaf(o.z, g1.y, fmaf(o.w, g1.w, a1))));
        }
        const float S = 0.04419417382415922f;
        float2 o; o.x = fmaf(a0, S, cb[0]); o.y = fmaf(a1, S, cb[1]);
        ((float2*)out)[base + t] = o;
    }
}

// ---------------------------------------------------------------------------

extern "C" void kernel_launch(void* const* d_in, const int* in_sizes, int n_in,
                              void* d_out, int out_size, void* d_ws, size_t ws_size,
                              hipStream_t stream) {
    const float* pos     = (const float*)d_in[0];
    const float* feat    = (const float*)d_in[1];
    const int*   esrc    = (const int*)d_in[2];
    const int*   edst    = (const int*)d_in[3];
    const float* fc1_w1  = (const float*)d_in[4];
    const float* fc1_w2  = (const float*)d_in[5];
    const float* core_w1 = (const float*)d_in[6];
    const float* core_w2 = (const float*)d_in[7];
    const float* fc3_w1  = (const float*)d_in[8];
    const float* fc3_w2  = (const float*)d_in[9];
    const float* conv_w  = (const float*)d_in[10];
    const float* conv_b  = (const float*)d_in[11];
    float* out = (float*)d_out;

    const int E = in_sizes[2];          // 1600000
    const int N = in_sizes[0] / 3;      // 100000
    const int nb = (N + 255) >> 8;      // 391

    float4* ebuf = (float4*)d_ws;                        // nb*BCAP float4
    int* ptmp  = (int*)(ebuf + (size_t)nb * BCAP);       // nb*BCAP int
    int* pidx  = ptmp + (size_t)nb * BCAP;               // nb*BCAP int
    float* xa  = (float*)(pidx + (size_t)nb * BCAP);     // 4N
    float* xb  = xa + (size_t)4 * N;                     // 4N
    int2* offs2 = (int2*)(xb + (size_t)4 * N);           // N
    int* gcur  = (int*)(offs2 + N);                      // nb
    float* gbuf = (float*)(gcur + ((nb + 3) & ~3));      // 128

    int nblk = (N + 127) / 128;         // 782 edge-balanced layer blocks

    hipMemsetAsync(gcur, 0, (size_t)nb * sizeof(int), stream);
    k_bin<<<(E + 2047) / 2048, 256, 0, stream>>>(esrc, edst, gcur, ptmp,
                                                 fc3_w2, conv_w, gbuf, E, nb);
    k_build<<<nb, 256, 0, stream>>>(gcur, ptmp, pidx, offs2, N, nb);
    {
        dim3 eg(BCAP / 256, nb);
        k_emb<<<eg, 256, 0, stream>>>(pos, gcur, pidx, ebuf);
    }

    k_layer_l1<<<nblk, 256, 0, stream>>>(feat, ebuf, offs2,
                                         fc1_w1, fc1_w2, xa, N);
    k_layer_core<<<nblk, 256, 0, stream>>>((const float4*)xa, ebuf, offs2,
                                           core_w1 + 0, core_w2 + 0, xb, N);
    k_layer_core<<<nblk, 256, 0, stream>>>((const float4*)xb, ebuf, offs2,
                                           core_w1 + 48, core_w2 + 768, xa, N);
    k_layer_core<<<nblk, 256, 0, stream>>>((const float4*)xa, ebuf, offs2,
                                           core_w1 + 96, core_w2 + 1536, xb, N);
    k_layer_fc3<<<nblk, 256, 0, stream>>>((const float4*)xb, ebuf, offs2,
                                          fc3_w1, gbuf, conv_b, out, N);
}

// Round 17
// 275.593 us; speedup vs baseline: 2.9313x; 2.9313x over previous
//
#include <hip/hip_runtime.h>

// ---------------------------------------------------------------------------
// Round 17: r16 retry — fix the nt-load compile error: __builtin_nontemporal_load
// requires a native vector type, not HIP_vector_type. Load via a clang
// ext_vector_type(4) alias and repack. Everything else identical to r14
// champion + nt edata streaming in the three layer kernels.
// ---------------------------------------------------------------------------

#define BCAP 4608      // bucket capacity: mean 4096 + 8 sigma
#define NBMAX 400

typedef float vfloat4 __attribute__((ext_vector_type(4)));

__device__ __forceinline__ float sus_f(float x) {
    return x > 0.0f ? __expf(-1.0f / x) : 0.0f;
}

__device__ __forceinline__ float uload(const float* p) {
    return __uint_as_float(__builtin_amdgcn_readfirstlane(__float_as_uint(*p)));
}

__device__ __forceinline__ float4 ntload4(const float4* p) {
    vfloat4 v = __builtin_nontemporal_load((const vfloat4*)p);
    return make_float4(v.x, v.y, v.z, v.w);
}

// --- pass 1: coarse binning, 4 B packed {src<<8 | dst&255}; block 0 also
// computes G[k][u][c] = sum_w fc3_w2[k][u*16+w] * conv_w[c][w] ---------------
__global__ __launch_bounds__(256) void k_bin(
    const int* __restrict__ src, const int* __restrict__ dst,
    int* __restrict__ gcur, int* __restrict__ ptmp,
    const float* __restrict__ fc3w2, const float* __restrict__ cw,
    float* __restrict__ gbuf,
    int nedges, int nb)
{
    __shared__ int cnt[NBMAX];
    __shared__ int gb[NBMAX];
    for (int b = threadIdx.x; b < nb; b += 256) cnt[b] = 0;
    __syncthreads();

    int base = blockIdx.x * 2048 + threadIdx.x * 8;
    int pk[8]; int bk[8]; short r[8];
    int ss[8], dd[8];
    if (base + 7 < nedges) {
        int4 s0 = *(const int4*)&src[base];
        int4 s1 = *(const int4*)&src[base + 4];
        int4 d0 = *(const int4*)&dst[base];
        int4 d1 = *(const int4*)&dst[base + 4];
        ss[0]=s0.x; ss[1]=s0.y; ss[2]=s0.z; ss[3]=s0.w;
        ss[4]=s1.x; ss[5]=s1.y; ss[6]=s1.z; ss[7]=s1.w;
        dd[0]=d0.x; dd[1]=d0.y; dd[2]=d0.z; dd[3]=d0.w;
        dd[4]=d1.x; dd[5]=d1.y; dd[6]=d1.z; dd[7]=d1.w;
        #pragma unroll
        for (int i = 0; i < 8; ++i) {
            int b = dd[i] >> 8;
            bk[i] = b;
            pk[i] = (ss[i] << 8) | (dd[i] & 255);
            r[i] = (short)atomicAdd(&cnt[b], 1);
        }
    } else {
        #pragma unroll
        for (int i = 0; i < 8; ++i) {
            int e = base + i;
            if (e < nedges) {
                int s = src[e], t = dst[e];
                int b = t >> 8;
                bk[i] = b;
                pk[i] = (s << 8) | (t & 255);
                r[i] = (short)atomicAdd(&cnt[b], 1);
            } else bk[i] = -1;
        }
    }
    __syncthreads();
    for (int b = threadIdx.x; b < nb; b += 256) {
        int c = cnt[b];
        gb[b] = c > 0 ? atomicAdd(&gcur[b], c) : 0;
    }
    __syncthreads();
    #pragma unroll
    for (int i = 0; i < 8; ++i) {
        if (bk[i] >= 0) {
            int p = gb[bk[i]] + (int)r[i];
            if (p < BCAP)   // statistically impossible overflow guard
                ptmp[bk[i] * BCAP + p] = pk[i];
        }
    }

    // fold in the tiny G-precompute (one block, independent of binning data)
    if (blockIdx.x == 0 && threadIdx.x < 128) {
        int idx = threadIdx.x;          // k*8 + u*2 + c
        int k = idx >> 3, u = (idx >> 1) & 3, c = idx & 1;
        float s = 0.0f;
        #pragma unroll
        for (int w = 0; w < 16; ++w)
            s = fmaf(fc3w2[k * 64 + u * 16 + w], cw[c * 16 + w], s);
        gbuf[idx] = s;
    }
}

// --- pass 2: per-bucket histogram/scan/permute (all in LDS, coalesced out) ---
__global__ __launch_bounds__(256) void k_build(
    const int* __restrict__ gcur, const int* __restrict__ ptmp,
    int* __restrict__ pidx, int2* __restrict__ offs2,
    int n, int nb)
{
    int b = blockIdx.x;
    int cnt = gcur[b]; if (cnt > BCAP) cnt = BCAP;

    __shared__ int stage[BCAP];
    __shared__ int perm[BCAP];
    __shared__ int deg[256];
    __shared__ int loffs[256];
    __shared__ int cur[256];

    const int* tin = ptmp + b * BCAP;
    for (int j = threadIdx.x; j < cnt; j += 256) stage[j] = tin[j];
    deg[threadIdx.x] = 0;
    __syncthreads();

    for (int j = threadIdx.x; j < cnt; j += 256)
        atomicAdd(&deg[stage[j] & 255], 1);
    __syncthreads();

    // exclusive scan deg -> loffs
    {
        int t = threadIdx.x;
        int v = deg[t];
        loffs[t] = v; __syncthreads();
        for (int off = 1; off < 256; off <<= 1) {
            int val = (t >= off) ? loffs[t - off] : 0;
            __syncthreads();
            loffs[t] += val;
            __syncthreads();
        }
        int incl = loffs[t];
        __syncthreads();
        loffs[t] = incl - v;
        cur[t] = incl - v;
        __syncthreads();
    }

    {
        int nid0 = b << 8;
        int nn = n - nid0; if (nn > 256) nn = 256;
        int t = threadIdx.x;
        if (t < nn) {
            int st = b * BCAP + loffs[t];
            offs2[nid0 + t] = make_int2(st, st + deg[t]);
        }
    }

    for (int j = threadIdx.x; j < cnt; j += 256) {
        int pkd = stage[j];
        perm[atomicAdd(&cur[pkd & 255], 1)] = pkd;
    }
    __syncthreads();

    int* tout = pidx + b * BCAP;
    for (int j = threadIdx.x; j < cnt; j += 256) tout[j] = perm[j];
}

// --- pass 3: edge-parallel emb, coalesced 16 B record writes -----------------
__global__ __launch_bounds__(256) void k_emb(
    const float* __restrict__ pos, const int* __restrict__ gcur,
    const int* __restrict__ pidx, float4* __restrict__ ebuf)
{
    int b = blockIdx.y;
    int j = blockIdx.x * 256 + threadIdx.x;
    if (j >= gcur[b]) return;
    int pkd = pidx[b * BCAP + j];
    int s = pkd >> 8;
    int t = (b << 8) | (pkd & 255);
    float dx = pos[3 * t + 0] - pos[3 * s + 0];
    float dy = pos[3 * t + 1] - pos[3 * s + 1];
    float dz = pos[3 * t + 2] - pos[3 * s + 2];
    float d = sqrtf(dx * dx + dy * dy + dz * dz);
    const float C = 1.14136f * 7.3890560989306495f; // 1.14136 * e^2
    float e0, e1, e2;
    { float f = (d - 0.75f) * (1.0f / 0.75f);
      e0 = C * sus_f(f + 1.0f) * sus_f(1.0f - f); }
    { float f = (d - 1.50f) * (1.0f / 0.75f);
      e1 = C * sus_f(f + 1.0f) * sus_f(1.0f - f); }
    { float f = (d - 2.25f) * (1.0f / 0.75f);
      e2 = C * sus_f(f + 1.0f) * sus_f(1.0f - f); }
    ebuf[(size_t)b * BCAP + j] = make_float4(__int_as_float(s), e0, e1, e2);
}

// --- layers: edge-split quads, partial outer product, LDS-W2 epilogue --------

__global__ __launch_bounds__(256) void k_node_l1(
    const float* __restrict__ feat, const float4* __restrict__ edata,
    const int2* __restrict__ offs2,
    const float* __restrict__ w1, const float* __restrict__ w2,
    float* __restrict__ xout, int n)
{
    __shared__ float lw[16 * 20];
    if (threadIdx.x < 192) {
        int k = threadIdx.x / 12, r = threadIdx.x % 12;
        lw[k * 20 + r] = w2[k * 12 + r];
    }
    __syncthreads();

    int g = blockIdx.x * 256 + threadIdx.x;
    int nd = g >> 2;
    if (nd >= n) return;
    int t = g & 3;

    float w1r[3][16];   // wave-uniform -> SGPRs
    #pragma unroll
    for (int j = 0; j < 3; ++j)
        #pragma unroll
        for (int k = 0; k < 16; ++k) w1r[j][k] = uload(&w1[j * 16 + k]);

    float O[16][3];
    #pragma unroll
    for (int k = 0; k < 16; ++k)
        #pragma unroll
        for (int u = 0; u < 3; ++u) O[k][u] = 0.0f;

    int2 se = offs2[nd];
    for (int e = se.x + t; e < se.y; e += 4) {
        float4 ed = ntload4(&edata[e]);
        int s = __float_as_int(ed.x);
        float f0 = feat[3 * s + 0], f1 = feat[3 * s + 1], f2 = feat[3 * s + 2];
        #pragma unroll
        for (int k = 0; k < 16; ++k) {
            float a = fmaf(ed.y, w1r[0][k], fmaf(ed.z, w1r[1][k], ed.w * w1r[2][k]));
            float h = a > 0.0f ? a : 0.0f;
            O[k][0] = fmaf(h, f0, O[k][0]);
            O[k][1] = fmaf(h, f1, O[k][1]);
            O[k][2] = fmaf(h, f2, O[k][2]);
        }
    }

    float p0 = 0.f, p1 = 0.f, p2 = 0.f, p3 = 0.f;
    #pragma unroll
    for (int k = 0; k < 16; ++k)
        #pragma unroll
        for (int u = 0; u < 3; ++u) {
            const float4 q = *(const float4*)&lw[k * 20 + u * 4];
            float o = O[k][u];
            p0 = fmaf(o, q.x, p0); p1 = fmaf(o, q.y, p1);
            p2 = fmaf(o, q.z, p2); p3 = fmaf(o, q.w, p3);
        }
    p0 += __shfl_xor(p0, 1); p1 += __shfl_xor(p1, 1);
    p2 += __shfl_xor(p2, 1); p3 += __shfl_xor(p3, 1);
    p0 += __shfl_xor(p0, 2); p1 += __shfl_xor(p1, 2);
    p2 += __shfl_xor(p2, 2); p3 += __shfl_xor(p3, 2);
    if (t == 0) {
        const float S = 0.051031036307982884f; // sqrt2/sqrt3/16
        float4 o; o.x = p0 * S; o.y = p1 * S; o.z = p2 * S; o.w = p3 * S;
        ((float4*)xout)[nd] = o;
    }
}

__global__ __launch_bounds__(256) void k_node_core(
    const float4* __restrict__ xin, const float4* __restrict__ edata,
    const int2* __restrict__ offs2,
    const float* __restrict__ w1, const float* __restrict__ w2,
    float* __restrict__ xout, int n)
{
    __shared__ float lw[16 * 20];
    {
        int idx = threadIdx.x;
        int k = idx >> 4, r = idx & 15;
        lw[k * 20 + r] = w2[k * 48 + r];
    }
    __syncthreads();

    int g = blockIdx.x * 256 + threadIdx.x;
    int nd = g >> 2;
    if (nd >= n) return;
    int t = g & 3;

    float w1r[3][16];   // wave-uniform -> SGPRs
    #pragma unroll
    for (int j = 0; j < 3; ++j)
        #pragma unroll
        for (int k = 0; k < 16; ++k) w1r[j][k] = uload(&w1[j * 16 + k]);

    float O[16][4];
    #pragma unroll
    for (int k = 0; k < 16; ++k)
        #pragma unroll
        for (int u = 0; u < 4; ++u) O[k][u] = 0.0f;

    int2 se = offs2[nd];
    for (int e = se.x + t; e < se.y; e += 4) {
        float4 ed = ntload4(&edata[e]);
        int s = __float_as_int(ed.x);
        float4 x = xin[s];
        #pragma unroll
        for (int k = 0; k < 16; ++k) {
            float a = fmaf(ed.y, w1r[0][k], fmaf(ed.z, w1r[1][k], ed.w * w1r[2][k]));
            float h = a > 0.0f ? a : 0.0f;
            O[k][0] = fmaf(h, x.x, O[k][0]);
            O[k][1] = fmaf(h, x.y, O[k][1]);
            O[k][2] = fmaf(h, x.z, O[k][2]);
            O[k][3] = fmaf(h, x.w, O[k][3]);
        }
    }

    float p0 = 0.f, p1 = 0.f, p2 = 0.f, p3 = 0.f;
    #pragma unroll
    for (int k = 0; k < 16; ++k)
        #pragma unroll
        for (int u = 0; u < 4; ++u) {
            const float4 q = *(const float4*)&lw[k * 20 + u * 4];
            float o = O[k][u];
            p0 = fmaf(o, q.x, p0); p1 = fmaf(o, q.y, p1);
            p2 = fmaf(o, q.z, p2); p3 = fmaf(o, q.w, p3);
        }
    p0 += __shfl_xor(p0, 1); p1 += __shfl_xor(p1, 1);
    p2 += __shfl_xor(p2, 1); p3 += __shfl_xor(p3, 1);
    p0 += __shfl_xor(p0, 2); p1 += __shfl_xor(p1, 2);
    p2 += __shfl_xor(p2, 2); p3 += __shfl_xor(p3, 2);
    if (t == 0) {
        const float S = 0.04419417382415922f; // sqrt2*0.5/16
        float4 o; o.x = p0 * S; o.y = p1 * S; o.z = p2 * S; o.w = p3 * S;
        ((float4*)xout)[nd] = o;
    }
}

// fc3 + folded 1x1 conv via precomputed G[16][4][2].
__global__ __launch_bounds__(256) void k_node_fc3_final(
    const float4* __restrict__ xin, const float4* __restrict__ edata,
    const int2* __restrict__ offs2,
    const float* __restrict__ w1, const float* __restrict__ gbuf,
    const float* __restrict__ cb,
    float* __restrict__ out, int n)
{
    __shared__ float lg[128];
    if (threadIdx.x < 128) lg[threadIdx.x] = gbuf[threadIdx.x];
    __syncthreads();

    int g = blockIdx.x * 256 + threadIdx.x;
    int nd = g >> 2;
    if (nd >= n) return;
    int t = g & 3;

    float w1r[3][16];   // wave-uniform -> SGPRs
    #pragma unroll
    for (int j = 0; j < 3; ++j)
        #pragma unroll
        for (int k = 0; k < 16; ++k) w1r[j][k] = uload(&w1[j * 16 + k]);

    float O[16][4];
    #pragma unroll
    for (int k = 0; k < 16; ++k)
        #pragma unroll
        for (int u = 0; u < 4; ++u) O[k][u] = 0.0f;

    int2 se = offs2[nd];
    for (int e = se.x + t; e < se.y; e += 4) {
        float4 ed = ntload4(&edata[e]);
        int s = __float_as_int(ed.x);
        float4 x = xin[s];
        #pragma unroll
        for (int k = 0; k < 16; ++k) {
            float a = fmaf(ed.y, w1r[0][k], fmaf(ed.z, w1r[1][k], ed.w * w1r[2][k]));
            float h = a > 0.0f ? a : 0.0f;
            O[k][0] = fmaf(h, x.x, O[k][0]);
            O[k][1] = fmaf(h, x.y, O[k][1]);
            O[k][2] = fmaf(h, x.z, O[k][2]);
            O[k][3] = fmaf(h, x.w, O[k][3]);
        }
    }

    float a0 = 0.f, a1 = 0.f;
    #pragma unroll
    for (int k = 0; k < 16; ++k)
        #pragma unroll
        for (int u = 0; u < 4; ++u) {
            float o = O[k][u];
            const float2 q = *(const float2*)&lg[(k * 4 + u) * 2];
            a0 = fmaf(o, q.x, a0);
            a1 = fmaf(o, q.y, a1);
        }
    a0 += __shfl_xor(a0, 1); a1 += __shfl_xor(a1, 1);
    a0 += __shfl_xor(a0, 2); a1 += __shfl_xor(a1, 2);
    if (t == 0) {
        const float S = 0.04419417382415922f;
        float2 o; o.x = fmaf(a0, S, cb[0]); o.y = fmaf(a1, S, cb[1]);
        ((float2*)out)[nd] = o;
    }
}

// ---------------------------------------------------------------------------

extern "C" void kernel_launch(void* const* d_in, const int* in_sizes, int n_in,
                              void* d_out, int out_size, void* d_ws, size_t ws_size,
                              hipStream_t stream) {
    const float* pos     = (const float*)d_in[0];
    const float* feat    = (const float*)d_in[1];
    const int*   esrc    = (const int*)d_in[2];
    const int*   edst    = (const int*)d_in[3];
    const float* fc1_w1  = (const float*)d_in[4];
    const float* fc1_w2  = (const float*)d_in[5];
    const float* core_w1 = (const float*)d_in[6];
    const float* core_w2 = (const float*)d_in[7];
    const float* fc3_w1  = (const float*)d_in[8];
    const float* fc3_w2  = (const float*)d_in[9];
    const float* conv_w  = (const float*)d_in[10];
    const float* conv_b  = (const float*)d_in[11];
    float* out = (float*)d_out;

    const int E = in_sizes[2];          // 1600000
    const int N = in_sizes[0] / 3;      // 100000
    const int nb = (N + 255) >> 8;      // 391

    float4* ebuf = (float4*)d_ws;                        // nb*BCAP float4
    int* ptmp  = (int*)(ebuf + (size_t)nb * BCAP);       // nb*BCAP int
    int* pidx  = ptmp + (size_t)nb * BCAP;               // nb*BCAP int
    float* xa  = (float*)(pidx + (size_t)nb * BCAP);     // 4N
    float* xb  = xa + (size_t)4 * N;                     // 4N
    int2* offs2 = (int2*)(xb + (size_t)4 * N);           // N
    int* gcur  = (int*)(offs2 + N);                      // nb
    float* gbuf = (float*)(gcur + ((nb + 3) & ~3));      // 128

    int g4 = (4 * N + 255) / 256;

    (void)hipMemsetAsync(gcur, 0, (size_t)nb * sizeof(int), stream);
    k_bin<<<(E + 2047) / 2048, 256, 0, stream>>>(esrc, edst, gcur, ptmp,
                                                 fc3_w2, conv_w, gbuf, E, nb);
    k_build<<<nb, 256, 0, stream>>>(gcur, ptmp, pidx, offs2, N, nb);
    {
        dim3 eg(BCAP / 256, nb);
        k_emb<<<eg, 256, 0, stream>>>(pos, gcur, pidx, ebuf);
    }

    k_node_l1<<<g4, 256, 0, stream>>>(feat, ebuf, offs2, fc1_w1, fc1_w2, xa, N);
    k_node_core<<<g4, 256, 0, stream>>>((const float4*)xa, ebuf, offs2,
                                        core_w1 + 0, core_w2 + 0, xb, N);
    k_node_core<<<g4, 256, 0, stream>>>((const float4*)xb, ebuf, offs2,
                                        core_w1 + 48, core_w2 + 768, xa, N);
    k_node_core<<<g4, 256, 0, stream>>>((const float4*)xa, ebuf, offs2,
                                        core_w1 + 96, core_w2 + 1536, xb, N);
    k_node_fc3_final<<<g4, 256, 0, stream>>>((const float4*)xb, ebuf, offs2,
                                             fc3_w1, gbuf, conv_b, out, N);
}

// Round 18
// 238.276 us; speedup vs baseline: 3.3904x; 1.1566x over previous
//
#include <hip/hip_runtime.h>

// ---------------------------------------------------------------------------
// Round 18: revert to the round-14 champion (236.5 us, reproduced twice).
// r17's non-temporal edata loads regressed (+39 us): edata has cross-quad
// L2 line reuse (4 quads/wave share 256 B runs) that nt bypassed. Falsified.
// Structure: binned CSR build (k_bin 4B packed -> k_build LDS permute ->
// k_emb edge-parallel emb) + 5 layer dispatches (edge-split quads, partial
// outer product O[16][u] by linearity of segment_sum, LDS-W2 epilogue,
// fc3 with the 1x1 conv folded into G at prep time).
// ---------------------------------------------------------------------------

#define BCAP 4608      // bucket capacity: mean 4096 + 8 sigma
#define NBMAX 400

__device__ __forceinline__ float sus_f(float x) {
    return x > 0.0f ? __expf(-1.0f / x) : 0.0f;
}

__device__ __forceinline__ float uload(const float* p) {
    return __uint_as_float(__builtin_amdgcn_readfirstlane(__float_as_uint(*p)));
}

// --- pass 1: coarse binning, 4 B packed {src<<8 | dst&255}; block 0 also
// computes G[k][u][c] = sum_w fc3_w2[k][u*16+w] * conv_w[c][w] ---------------
__global__ __launch_bounds__(256) void k_bin(
    const int* __restrict__ src, const int* __restrict__ dst,
    int* __restrict__ gcur, int* __restrict__ ptmp,
    const float* __restrict__ fc3w2, const float* __restrict__ cw,
    float* __restrict__ gbuf,
    int nedges, int nb)
{
    __shared__ int cnt[NBMAX];
    __shared__ int gb[NBMAX];
    for (int b = threadIdx.x; b < nb; b += 256) cnt[b] = 0;
    __syncthreads();

    int base = blockIdx.x * 2048 + threadIdx.x * 8;
    int pk[8]; int bk[8]; short r[8];
    int ss[8], dd[8];
    if (base + 7 < nedges) {
        int4 s0 = *(const int4*)&src[base];
        int4 s1 = *(const int4*)&src[base + 4];
        int4 d0 = *(const int4*)&dst[base];
        int4 d1 = *(const int4*)&dst[base + 4];
        ss[0]=s0.x; ss[1]=s0.y; ss[2]=s0.z; ss[3]=s0.w;
        ss[4]=s1.x; ss[5]=s1.y; ss[6]=s1.z; ss[7]=s1.w;
        dd[0]=d0.x; dd[1]=d0.y; dd[2]=d0.z; dd[3]=d0.w;
        dd[4]=d1.x; dd[5]=d1.y; dd[6]=d1.z; dd[7]=d1.w;
        #pragma unroll
        for (int i = 0; i < 8; ++i) {
            int b = dd[i] >> 8;
            bk[i] = b;
            pk[i] = (ss[i] << 8) | (dd[i] & 255);
            r[i] = (short)atomicAdd(&cnt[b], 1);
        }
    } else {
        #pragma unroll
        for (int i = 0; i < 8; ++i) {
            int e = base + i;
            if (e < nedges) {
                int s = src[e], t = dst[e];
                int b = t >> 8;
                bk[i] = b;
                pk[i] = (s << 8) | (t & 255);
                r[i] = (short)atomicAdd(&cnt[b], 1);
            } else bk[i] = -1;
        }
    }
    __syncthreads();
    for (int b = threadIdx.x; b < nb; b += 256) {
        int c = cnt[b];
        gb[b] = c > 0 ? atomicAdd(&gcur[b], c) : 0;
    }
    __syncthreads();
    #pragma unroll
    for (int i = 0; i < 8; ++i) {
        if (bk[i] >= 0) {
            int p = gb[bk[i]] + (int)r[i];
            if (p < BCAP)   // statistically impossible overflow guard
                ptmp[bk[i] * BCAP + p] = pk[i];
        }
    }

    // fold in the tiny G-precompute (one block, independent of binning data)
    if (blockIdx.x == 0 && threadIdx.x < 128) {
        int idx = threadIdx.x;          // k*8 + u*2 + c
        int k = idx >> 3, u = (idx >> 1) & 3, c = idx & 1;
        float s = 0.0f;
        #pragma unroll
        for (int w = 0; w < 16; ++w)
            s = fmaf(fc3w2[k * 64 + u * 16 + w], cw[c * 16 + w], s);
        gbuf[idx] = s;
    }
}

// --- pass 2: per-bucket histogram/scan/permute (all in LDS, coalesced out) ---
__global__ __launch_bounds__(256) void k_build(
    const int* __restrict__ gcur, const int* __restrict__ ptmp,
    int* __restrict__ pidx, int2* __restrict__ offs2,
    int n, int nb)
{
    int b = blockIdx.x;
    int cnt = gcur[b]; if (cnt > BCAP) cnt = BCAP;

    __shared__ int stage[BCAP];
    __shared__ int perm[BCAP];
    __shared__ int deg[256];
    __shared__ int loffs[256];
    __shared__ int cur[256];

    const int* tin = ptmp + b * BCAP;
    for (int j = threadIdx.x; j < cnt; j += 256) stage[j] = tin[j];
    deg[threadIdx.x] = 0;
    __syncthreads();

    for (int j = threadIdx.x; j < cnt; j += 256)
        atomicAdd(&deg[stage[j] & 255], 1);
    __syncthreads();

    // exclusive scan deg -> loffs
    {
        int t = threadIdx.x;
        int v = deg[t];
        loffs[t] = v; __syncthreads();
        for (int off = 1; off < 256; off <<= 1) {
            int val = (t >= off) ? loffs[t - off] : 0;
            __syncthreads();
            loffs[t] += val;
            __syncthreads();
        }
        int incl = loffs[t];
        __syncthreads();
        loffs[t] = incl - v;
        cur[t] = incl - v;
        __syncthreads();
    }

    {
        int nid0 = b << 8;
        int nn = n - nid0; if (nn > 256) nn = 256;
        int t = threadIdx.x;
        if (t < nn) {
            int st = b * BCAP + loffs[t];
            offs2[nid0 + t] = make_int2(st, st + deg[t]);
        }
    }

    for (int j = threadIdx.x; j < cnt; j += 256) {
        int pkd = stage[j];
        perm[atomicAdd(&cur[pkd & 255], 1)] = pkd;
    }
    __syncthreads();

    int* tout = pidx + b * BCAP;
    for (int j = threadIdx.x; j < cnt; j += 256) tout[j] = perm[j];
}

// --- pass 3: edge-parallel emb, coalesced 16 B record writes -----------------
__global__ __launch_bounds__(256) void k_emb(
    const float* __restrict__ pos, const int* __restrict__ gcur,
    const int* __restrict__ pidx, float4* __restrict__ ebuf)
{
    int b = blockIdx.y;
    int j = blockIdx.x * 256 + threadIdx.x;
    if (j >= gcur[b]) return;
    int pkd = pidx[b * BCAP + j];
    int s = pkd >> 8;
    int t = (b << 8) | (pkd & 255);
    float dx = pos[3 * t + 0] - pos[3 * s + 0];
    float dy = pos[3 * t + 1] - pos[3 * s + 1];
    float dz = pos[3 * t + 2] - pos[3 * s + 2];
    float d = sqrtf(dx * dx + dy * dy + dz * dz);
    const float C = 1.14136f * 7.3890560989306495f; // 1.14136 * e^2
    float e0, e1, e2;
    { float f = (d - 0.75f) * (1.0f / 0.75f);
      e0 = C * sus_f(f + 1.0f) * sus_f(1.0f - f); }
    { float f = (d - 1.50f) * (1.0f / 0.75f);
      e1 = C * sus_f(f + 1.0f) * sus_f(1.0f - f); }
    { float f = (d - 2.25f) * (1.0f / 0.75f);
      e2 = C * sus_f(f + 1.0f) * sus_f(1.0f - f); }
    ebuf[(size_t)b * BCAP + j] = make_float4(__int_as_float(s), e0, e1, e2);
}

// --- layers: edge-split quads, partial outer product, LDS-W2 epilogue --------

__global__ __launch_bounds__(256) void k_node_l1(
    const float* __restrict__ feat, const float4* __restrict__ edata,
    const int2* __restrict__ offs2,
    const float* __restrict__ w1, const float* __restrict__ w2,
    float* __restrict__ xout, int n)
{
    __shared__ float lw[16 * 20];
    if (threadIdx.x < 192) {
        int k = threadIdx.x / 12, r = threadIdx.x % 12;
        lw[k * 20 + r] = w2[k * 12 + r];
    }
    __syncthreads();

    int g = blockIdx.x * 256 + threadIdx.x;
    int nd = g >> 2;
    if (nd >= n) return;
    int t = g & 3;

    float w1r[3][16];   // wave-uniform -> SGPRs
    #pragma unroll
    for (int j = 0; j < 3; ++j)
        #pragma unroll
        for (int k = 0; k < 16; ++k) w1r[j][k] = uload(&w1[j * 16 + k]);

    float O[16][3];
    #pragma unroll
    for (int k = 0; k < 16; ++k)
        #pragma unroll
        for (int u = 0; u < 3; ++u) O[k][u] = 0.0f;

    int2 se = offs2[nd];
    for (int e = se.x + t; e < se.y; e += 4) {
        float4 ed = edata[e];
        int s = __float_as_int(ed.x);
        float f0 = feat[3 * s + 0], f1 = feat[3 * s + 1], f2 = feat[3 * s + 2];
        #pragma unroll
        for (int k = 0; k < 16; ++k) {
            float a = fmaf(ed.y, w1r[0][k], fmaf(ed.z, w1r[1][k], ed.w * w1r[2][k]));
            float h = a > 0.0f ? a : 0.0f;
            O[k][0] = fmaf(h, f0, O[k][0]);
            O[k][1] = fmaf(h, f1, O[k][1]);
            O[k][2] = fmaf(h, f2, O[k][2]);
        }
    }

    float p0 = 0.f, p1 = 0.f, p2 = 0.f, p3 = 0.f;
    #pragma unroll
    for (int k = 0; k < 16; ++k)
        #pragma unroll
        for (int u = 0; u < 3; ++u) {
            const float4 q = *(const float4*)&lw[k * 20 + u * 4];
            float o = O[k][u];
            p0 = fmaf(o, q.x, p0); p1 = fmaf(o, q.y, p1);
            p2 = fmaf(o, q.z, p2); p3 = fmaf(o, q.w, p3);
        }
    p0 += __shfl_xor(p0, 1); p1 += __shfl_xor(p1, 1);
    p2 += __shfl_xor(p2, 1); p3 += __shfl_xor(p3, 1);
    p0 += __shfl_xor(p0, 2); p1 += __shfl_xor(p1, 2);
    p2 += __shfl_xor(p2, 2); p3 += __shfl_xor(p3, 2);
    if (t == 0) {
        const float S = 0.051031036307982884f; // sqrt2/sqrt3/16
        float4 o; o.x = p0 * S; o.y = p1 * S; o.z = p2 * S; o.w = p3 * S;
        ((float4*)xout)[nd] = o;
    }
}

__global__ __launch_bounds__(256) void k_node_core(
    const float4* __restrict__ xin, const float4* __restrict__ edata,
    const int2* __restrict__ offs2,
    const float* __restrict__ w1, const float* __restrict__ w2,
    float* __restrict__ xout, int n)
{
    __shared__ float lw[16 * 20];
    {
        int idx = threadIdx.x;
        int k = idx >> 4, r = idx & 15;
        lw[k * 20 + r] = w2[k * 48 + r];
    }
    __syncthreads();

    int g = blockIdx.x * 256 + threadIdx.x;
    int nd = g >> 2;
    if (nd >= n) return;
    int t = g & 3;

    float w1r[3][16];   // wave-uniform -> SGPRs
    #pragma unroll
    for (int j = 0; j < 3; ++j)
        #pragma unroll
        for (int k = 0; k < 16; ++k) w1r[j][k] = uload(&w1[j * 16 + k]);

    float O[16][4];
    #pragma unroll
    for (int k = 0; k < 16; ++k)
        #pragma unroll
        for (int u = 0; u < 4; ++u) O[k][u] = 0.0f;

    int2 se = offs2[nd];
    for (int e = se.x + t; e < se.y; e += 4) {
        float4 ed = edata[e];
        int s = __float_as_int(ed.x);
        float4 x = xin[s];
        #pragma unroll
        for (int k = 0; k < 16; ++k) {
            float a = fmaf(ed.y, w1r[0][k], fmaf(ed.z, w1r[1][k], ed.w * w1r[2][k]));
            float h = a > 0.0f ? a : 0.0f;
            O[k][0] = fmaf(h, x.x, O[k][0]);
            O[k][1] = fmaf(h, x.y, O[k][1]);
            O[k][2] = fmaf(h, x.z, O[k][2]);
            O[k][3] = fmaf(h, x.w, O[k][3]);
        }
    }

    float p0 = 0.f, p1 = 0.f, p2 = 0.f, p3 = 0.f;
    #pragma unroll
    for (int k = 0; k < 16; ++k)
        #pragma unroll
        for (int u = 0; u < 4; ++u) {
            const float4 q = *(const float4*)&lw[k * 20 + u * 4];
            float o = O[k][u];
            p0 = fmaf(o, q.x, p0); p1 = fmaf(o, q.y, p1);
            p2 = fmaf(o, q.z, p2); p3 = fmaf(o, q.w, p3);
        }
    p0 += __shfl_xor(p0, 1); p1 += __shfl_xor(p1, 1);
    p2 += __shfl_xor(p2, 1); p3 += __shfl_xor(p3, 1);
    p0 += __shfl_xor(p0, 2); p1 += __shfl_xor(p1, 2);
    p2 += __shfl_xor(p2, 2); p3 += __shfl_xor(p3, 2);
    if (t == 0) {
        const float S = 0.04419417382415922f; // sqrt2*0.5/16
        float4 o; o.x = p0 * S; o.y = p1 * S; o.z = p2 * S; o.w = p3 * S;
        ((float4*)xout)[nd] = o;
    }
}

// fc3 + folded 1x1 conv via precomputed G[16][4][2].
__global__ __launch_bounds__(256) void k_node_fc3_final(
    const float4* __restrict__ xin, const float4* __restrict__ edata,
    const int2* __restrict__ offs2,
    const float* __restrict__ w1, const float* __restrict__ gbuf,
    const float* __restrict__ cb,
    float* __restrict__ out, int n)
{
    __shared__ float lg[128];
    if (threadIdx.x < 128) lg[threadIdx.x] = gbuf[threadIdx.x];
    __syncthreads();

    int g = blockIdx.x * 256 + threadIdx.x;
    int nd = g >> 2;
    if (nd >= n) return;
    int t = g & 3;

    float w1r[3][16];   // wave-uniform -> SGPRs
    #pragma unroll
    for (int j = 0; j < 3; ++j)
        #pragma unroll
        for (int k = 0; k < 16; ++k) w1r[j][k] = uload(&w1[j * 16 + k]);

    float O[16][4];
    #pragma unroll
    for (int k = 0; k < 16; ++k)
        #pragma unroll
        for (int u = 0; u < 4; ++u) O[k][u] = 0.0f;

    int2 se = offs2[nd];
    for (int e = se.x + t; e < se.y; e += 4) {
        float4 ed = edata[e];
        int s = __float_as_int(ed.x);
        float4 x = xin[s];
        #pragma unroll
        for (int k = 0; k < 16; ++k) {
            float a = fmaf(ed.y, w1r[0][k], fmaf(ed.z, w1r[1][k], ed.w * w1r[2][k]));
            float h = a > 0.0f ? a : 0.0f;
            O[k][0] = fmaf(h, x.x, O[k][0]);
            O[k][1] = fmaf(h, x.y, O[k][1]);
            O[k][2] = fmaf(h, x.z, O[k][2]);
            O[k][3] = fmaf(h, x.w, O[k][3]);
        }
    }

    float a0 = 0.f, a1 = 0.f;
    #pragma unroll
    for (int k = 0; k < 16; ++k)
        #pragma unroll
        for (int u = 0; u < 4; ++u) {
            float o = O[k][u];
            const float2 q = *(const float2*)&lg[(k * 4 + u) * 2];
            a0 = fmaf(o, q.x, a0);
            a1 = fmaf(o, q.y, a1);
        }
    a0 += __shfl_xor(a0, 1); a1 += __shfl_xor(a1, 1);
    a0 += __shfl_xor(a0, 2); a1 += __shfl_xor(a1, 2);
    if (t == 0) {
        const float S = 0.04419417382415922f;
        float2 o; o.x = fmaf(a0, S, cb[0]); o.y = fmaf(a1, S, cb[1]);
        ((float2*)out)[nd] = o;
    }
}

// ---------------------------------------------------------------------------

extern "C" void kernel_launch(void* const* d_in, const int* in_sizes, int n_in,
                              void* d_out, int out_size, void* d_ws, size_t ws_size,
                              hipStream_t stream) {
    const float* pos     = (const float*)d_in[0];
    const float* feat    = (const float*)d_in[1];
    const int*   esrc    = (const int*)d_in[2];
    const int*   edst    = (const int*)d_in[3];
    const float* fc1_w1  = (const float*)d_in[4];
    const float* fc1_w2  = (const float*)d_in[5];
    const float* core_w1 = (const float*)d_in[6];
    const float* core_w2 = (const float*)d_in[7];
    const float* fc3_w1  = (const float*)d_in[8];
    const float* fc3_w2  = (const float*)d_in[9];
    const float* conv_w  = (const float*)d_in[10];
    const float* conv_b  = (const float*)d_in[11];
    float* out = (float*)d_out;

    const int E = in_sizes[2];          // 1600000
    const int N = in_sizes[0] / 3;      // 100000
    const int nb = (N + 255) >> 8;      // 391

    float4* ebuf = (float4*)d_ws;                        // nb*BCAP float4
    int* ptmp  = (int*)(ebuf + (size_t)nb * BCAP);       // nb*BCAP int
    int* pidx  = ptmp + (size_t)nb * BCAP;               // nb*BCAP int
    float* xa  = (float*)(pidx + (size_t)nb * BCAP);     // 4N
    float* xb  = xa + (size_t)4 * N;                     // 4N
    int2* offs2 = (int2*)(xb + (size_t)4 * N);           // N
    int* gcur  = (int*)(offs2 + N);                      // nb
    float* gbuf = (float*)(gcur + ((nb + 3) & ~3));      // 128

    int g4 = (4 * N + 255) / 256;

    (void)hipMemsetAsync(gcur, 0, (size_t)nb * sizeof(int), stream);
    k_bin<<<(E + 2047) / 2048, 256, 0, stream>>>(esrc, edst, gcur, ptmp,
                                                 fc3_w2, conv_w, gbuf, E, nb);
    k_build<<<nb, 256, 0, stream>>>(gcur, ptmp, pidx, offs2, N, nb);
    {
        dim3 eg(BCAP / 256, nb);
        k_emb<<<eg, 256, 0, stream>>>(pos, gcur, pidx, ebuf);
    }

    k_node_l1<<<g4, 256, 0, stream>>>(feat, ebuf, offs2, fc1_w1, fc1_w2, xa, N);
    k_node_core<<<g4, 256, 0, stream>>>((const float4*)xa, ebuf, offs2,
                                        core_w1 + 0, core_w2 + 0, xb, N);
    k_node_core<<<g4, 256, 0, stream>>>((const float4*)xb, ebuf, offs2,
                                        core_w1 + 48, core_w2 + 768, xa, N);
    k_node_core<<<g4, 256, 0, stream>>>((const float4*)xa, ebuf, offs2,
                                        core_w1 + 96, core_w2 + 1536, xb, N);
    k_node_fc3_final<<<g4, 256, 0, stream>>>((const float4*)xb, ebuf, offs2,
                                             fc3_w1, gbuf, conv_b, out, N);
}